// Round 7
// baseline (449.151 us; speedup 1.0000x reference)
//
#include <hip/hip_runtime.h>
#include <hip/hip_bf16.h>
#include <stdint.h>

// LSTM cell fused, three-kernel version:
//   pack: weights -> bf16 MFMA-B-fragment layout (1 MB in d_ws), bias packed
//   K1:   gates GEMM. A: f32 loaded straight into REGISTERS (coalesced
//         dwordx4, prefetched one step ahead), converted to bf16 fragments
//         via v_cvt_pk_bf16_f32. B: bf16 via global_load_lds into dbuf LDS
//         (32 KB). Per wave-step: 4 ds_read_b128 + 16 cvt_pk + 16 MFMA.
//         Epilogue: bias + sigmoid/tanh gates + cell update -> writes nc, nh.
//   K2:   per-row log_softmax finalize -> writes output 0.
// B=65536, IN=H=256, K=512, 4H=1024 gate cols.

#define BH 16777216  // 65536*256

typedef float f32x4 __attribute__((ext_vector_type(4)));
typedef short short8 __attribute__((ext_vector_type(8)));

__device__ __forceinline__ unsigned short f2bf(float f) {
    union { float f; unsigned u; } v; v.f = f;
    unsigned u = v.u;
    return (unsigned short)((u + 0x7fffu + ((u >> 16) & 1u)) >> 16);
}

__device__ __forceinline__ unsigned pack2bf(float a, float b) {
    __hip_bfloat162 h = __float22bfloat162_rn(make_float2(a, b));
    union { __hip_bfloat162 h; unsigned u; } v; v.h = h;
    return v.u;  // v_cvt_pk_bf16_f32
}

__device__ __forceinline__ float sigm(float x) { return 1.f / (1.f + __expf(-x)); }
__device__ __forceinline__ float tanh_(float x) { return 1.f - 2.f / (1.f + __expf(2.f * x)); }

__device__ __forceinline__ void glds16(const void* g, const void* l) {
    __builtin_amdgcn_global_load_lds(
        (const __attribute__((address_space(1))) unsigned int*)(uintptr_t)g,
        (__attribute__((address_space(3))) unsigned int*)(unsigned int)(uintptr_t)l,
        16, 0, 0);
}

// ---- pack: wpack[hg][step(16)][Nt(16)][lane(64)][j(8)] bf16 ----
// col cp = hg*256 + Nt*16 + n16 ; Nt = wc*4 + gate ; h = hg*64 + wc*16 + n16
// value = W[gate][h][k], k = step*32 + (lane>>4)*8 + j
__global__ __launch_bounds__(256) void pack_kernel(
    const float* __restrict__ Wif, const float* __restrict__ Wii,
    const float* __restrict__ Wio, const float* __restrict__ Wig,
    const float* __restrict__ Whf, const float* __restrict__ Whi,
    const float* __restrict__ Who, const float* __restrict__ Whg,
    const float* __restrict__ bif, const float* __restrict__ bii,
    const float* __restrict__ bio, const float* __restrict__ big,
    const float* __restrict__ bhf, const float* __restrict__ bhi,
    const float* __restrict__ bho, const float* __restrict__ bhg,
    unsigned short* __restrict__ wpack, float* __restrict__ bpack)
{
    const int t = blockIdx.x * 256 + threadIdx.x;   // 0..65535
    const int n16  = t & 15;
    const int kg   = (t >> 4) & 3;
    const int Nt   = (t >> 6) & 15;
    const int step = (t >> 10) & 15;
    const int hg   = t >> 14;
    const int gate = Nt & 3;
    const int wc   = Nt >> 2;
    const int h    = hg * 64 + wc * 16 + n16;
    const int k0   = step * 32 + kg * 8;

    const float* Wi = (gate == 0) ? Wif : (gate == 1) ? Wii : (gate == 2) ? Wio : Wig;
    const float* Wh = (gate == 0) ? Whf : (gate == 1) ? Whi : (gate == 2) ? Who : Whg;
    const float* src = (k0 < 256) ? (Wi + h * 256 + k0) : (Wh + h * 256 + (k0 - 256));

    unsigned pk[4];
#pragma unroll
    for (int p = 0; p < 4; ++p)
        pk[p] = (unsigned)f2bf(src[p * 2]) | ((unsigned)f2bf(src[p * 2 + 1]) << 16);
    uint4 o4 = {pk[0], pk[1], pk[2], pk[3]};
    *(uint4*)&wpack[(size_t)t * 8] = o4;

    if (t < 1024) {
        const int cp = t;
        const int n2 = cp & 15, Nt2 = (cp >> 4) & 15, hg2 = cp >> 8;
        const int g2 = Nt2 & 3, wc2 = Nt2 >> 2;
        const int h2 = hg2 * 64 + wc2 * 16 + n2;
        const float* bi = (g2 == 0) ? bif : (g2 == 1) ? bii : (g2 == 2) ? bio : big;
        const float* bh = (g2 == 0) ? bhf : (g2 == 1) ? bhi : (g2 == 2) ? bho : bhg;
        bpack[cp] = bi[h2] + bh[h2];
    }
}

// ---- K1: GEMM + gates. grid 2048 = 512 panels x 4 hg, block 512 (8 waves) ----
// A in registers (f32, prefetched one step ahead, cvt_pk -> bf16 frags);
// B in double-buffered LDS via global_load_lds.
__global__ __launch_bounds__(512, 4) void lstm_gemm_kernel(
    const float* __restrict__ input, const float* __restrict__ hidden,
    const float* __restrict__ cell,
    const unsigned short* __restrict__ wpack, const float* __restrict__ bpack,
    float* __restrict__ out)
{
    __shared__ unsigned short Bbuf[2][8192];   // 2 x 16 KB

    // XCD-bijective swizzle (2048 % 8 == 0): each XCD gets 64 panels x 4 hg
    const int swz = (blockIdx.x & 7) * 256 + (blockIdx.x >> 3);
    const int hg    = swz & 3;
    const int panel = swz >> 2;
    const int row0  = panel * 128;

    const int tid = threadIdx.x;
    const int w = tid >> 6, l = tid & 63;
    const int wr = w >> 2, wc = w & 3;
    const int n16l = l & 15;

    const unsigned short* wsrc = wpack + (size_t)hg * 131072 + w * 1024 + l * 8;

    // A fragment row offsets (in floats): frag m -> row row0+wr*64+m*16+(l&15),
    // k-offset within step: (l>>4)*8
    size_t arow[4];
#pragma unroll
    for (int m = 0; m < 4; ++m)
        arow[m] = (size_t)(row0 + wr * 64 + m * 16 + n16l) * 256 + ((l >> 4) * 8);

    // ---- prologue: stage B0, load A0 into regs ----
    glds16(wsrc, &Bbuf[0][w * 1024]);
    glds16(wsrc + 512, &Bbuf[0][w * 1024 + 512]);
    float4 a0[4], a1[4];
#pragma unroll
    for (int m = 0; m < 4; ++m) {
        a0[m] = *(const float4*)(input + arow[m]);
        a1[m] = *(const float4*)(input + arow[m] + 4);
    }
    __syncthreads();

    f32x4 acc[4][4] = {};

#pragma unroll 2
    for (int step = 0; step < 16; ++step) {
        const int cb = step & 1, nb = cb ^ 1;
        // issue next B staging first (latency hidden under this step's MFMA)
        if (step < 15) {
            glds16(wsrc + (size_t)(step + 1) * 8192, &Bbuf[nb][w * 1024]);
            glds16(wsrc + (size_t)(step + 1) * 8192 + 512, &Bbuf[nb][w * 1024 + 512]);
        }
        // convert this step's A regs -> bf16 fragments
        short8 Af[4];
#pragma unroll
        for (int m = 0; m < 4; ++m) {
            union { uint4 u; short8 s; } cv;
            cv.u.x = pack2bf(a0[m].x, a0[m].y); cv.u.y = pack2bf(a0[m].z, a0[m].w);
            cv.u.z = pack2bf(a1[m].x, a1[m].y); cv.u.w = pack2bf(a1[m].z, a1[m].w);
            Af[m] = cv.s;
        }
        // prefetch next step's A into regs
        if (step < 15) {
            const int kn = (step + 1) * 32;
            const float* xb = (kn < 256) ? (input + kn) : (hidden + (kn - 256));
#pragma unroll
            for (int m = 0; m < 4; ++m) {
                a0[m] = *(const float4*)(xb + arow[m]);
                a1[m] = *(const float4*)(xb + arow[m] + 4);
            }
        }
        // B from LDS, column-at-a-time to cap register pressure
        __builtin_amdgcn_s_setprio(1);
#pragma unroll
        for (int n = 0; n < 4; ++n) {
            short8 Bf = *(const short8*)&Bbuf[cb][(((wc * 4 + n) * 64 + l) << 3)];
#pragma unroll
            for (int m = 0; m < 4; ++m)
                acc[m][n] = __builtin_amdgcn_mfma_f32_16x16x32_bf16(Af[m], Bf, acc[m][n], 0, 0, 0);
        }
        __builtin_amdgcn_s_setprio(0);
        __syncthreads();
    }

    // ---- epilogue: bias + activations + cell update ----
    const int lrow = l >> 4;
    const int hcol = hg * 64 + wc * 16 + n16l;
    float bias[4];
#pragma unroll
    for (int n = 0; n < 4; ++n)
        bias[n] = bpack[hg * 256 + wc * 64 + n * 16 + n16l];

#pragma unroll
    for (int m = 0; m < 4; ++m) {
#pragma unroll
        for (int rr = 0; rr < 4; ++rr) {
            const size_t rg_ = (size_t)row0 + wr * 64 + m * 16 + lrow * 4 + rr;
            const float fv = sigm(acc[m][0][rr] + bias[0]);
            const float iv = sigm(acc[m][1][rr] + bias[1]);
            const float ov = sigm(acc[m][2][rr] + bias[2]);
            const float gv = tanh_(acc[m][3][rr] + bias[3]);
            const float cv = cell[rg_ * 256 + hcol];
            const float nc = fv * cv + iv * gv;
            const float nhv = ov * tanh_(nc);
            out[(size_t)2 * BH + rg_ * 256 + hcol] = nc;
            out[(size_t)BH + rg_ * 256 + hcol] = nhv;
        }
    }
}

// ---- K2: log_softmax finalize. out[0..BH) = nh - log(sum(exp(nh))) ----
__global__ __launch_bounds__(256) void softmax_kernel(
    const float* __restrict__ nh, float* __restrict__ outp)
{
    const int w = threadIdx.x >> 6, l = threadIdx.x & 63;
#pragma unroll 1
    for (int it = 0; it < 8; ++it) {
        const size_t row = (size_t)it * 8192 + blockIdx.x * 4 + w;
        float4 v = *(const float4*)(nh + row * 256 + l * 4);
        float s = __expf(v.x) + __expf(v.y) + __expf(v.z) + __expf(v.w);
#pragma unroll
        for (int m = 1; m < 64; m <<= 1) s += __shfl_xor(s, m);
        const float lz = __logf(s);
        float4 o = {v.x - lz, v.y - lz, v.z - lz, v.w - lz};
        *(float4*)(outp + row * 256 + l * 4) = o;
    }
}

extern "C" void kernel_launch(void* const* d_in, const int* in_sizes, int n_in,
                              void* d_out, int out_size, void* d_ws, size_t ws_size,
                              hipStream_t stream)
{
    const float* input  = (const float*)d_in[0];
    const float* hidden = (const float*)d_in[1];
    const float* cell   = (const float*)d_in[2];
    const float* Wif = (const float*)d_in[3];  const float* bif = (const float*)d_in[4];
    const float* Wii = (const float*)d_in[5];  const float* bii = (const float*)d_in[6];
    const float* Wio = (const float*)d_in[7];  const float* bio = (const float*)d_in[8];
    const float* Wig = (const float*)d_in[9];  const float* big = (const float*)d_in[10];
    const float* Whf = (const float*)d_in[11]; const float* bhf = (const float*)d_in[12];
    const float* Whi = (const float*)d_in[13]; const float* bhi = (const float*)d_in[14];
    const float* Who = (const float*)d_in[15]; const float* bho = (const float*)d_in[16];
    const float* Whg = (const float*)d_in[17]; const float* bhg = (const float*)d_in[18];

    unsigned short* wpack = (unsigned short*)d_ws;                 // 1 MB
    float* bpack = (float*)((char*)d_ws + (size_t)1024 * 512 * 2); // 4 KB

    float* out = (float*)d_out;

    hipLaunchKernelGGL(pack_kernel, dim3(256), dim3(256), 0, stream,
        Wif, Wii, Wio, Wig, Whf, Whi, Who, Whg,
        bif, bii, bio, big, bhf, bhi, bho, bhg, wpack, bpack);

    hipLaunchKernelGGL(lstm_gemm_kernel, dim3(2048), dim3(512), 0, stream,
        input, hidden, cell, wpack, bpack, out);

    hipLaunchKernelGGL(softmax_kernel, dim3(2048), dim3(256), 0, stream,
        out + (size_t)BH, out);
}

// Round 8
// 171.900 us; speedup vs baseline: 2.6129x; 2.6129x over previous
//
#include <hip/hip_runtime.h>
#include <hip/hip_bf16.h>
#include <stdint.h>

// LSTM cell fused, four-kernel version:
//   pack:    weights -> bf16 MFMA-B-fragment layout (1 MB in d_ws), bias packed
//   convert: X=[input|hidden] f32 -> bf16 in A-fragment glds order (64 MB,
//            stored in d_out[0:BH) which is free until K2 overwrites it)
//   K1:      gates GEMM, pure glds staging, TRIPLE-buffered LDS, counted
//            vmcnt(3), ONE barrier per K-step (stage-2-ahead makes the
//            read-done barrier redundant), STAGE issued before MFMA cluster,
//            setprio around MFMA. 16 MFMA + 8 ds_read_b128 per wave-step.
//   K2:      per-row log_softmax finalize -> writes output 0
// B=65536, IN=H=256, K=512, 4H=1024 gate cols.

#define BH 16777216  // 65536*256

typedef float f32x4 __attribute__((ext_vector_type(4)));
typedef short short8 __attribute__((ext_vector_type(8)));

__device__ __forceinline__ unsigned short f2bf(float f) {
    union { float f; unsigned u; } v; v.f = f;
    unsigned u = v.u;
    return (unsigned short)((u + 0x7fffu + ((u >> 16) & 1u)) >> 16);
}

__device__ __forceinline__ unsigned pack2bf(float a, float b) {
    __hip_bfloat162 h = __float22bfloat162_rn(make_float2(a, b));
    union { __hip_bfloat162 h; unsigned u; } v; v.h = h;
    return v.u;  // v_cvt_pk_bf16_f32
}

__device__ __forceinline__ float sigm(float x) { return 1.f / (1.f + __expf(-x)); }
__device__ __forceinline__ float tanh_(float x) { return 1.f - 2.f / (1.f + __expf(2.f * x)); }

__device__ __forceinline__ void glds16(const void* g, const void* l) {
    __builtin_amdgcn_global_load_lds(
        (const __attribute__((address_space(1))) unsigned int*)(uintptr_t)g,
        (__attribute__((address_space(3))) unsigned int*)(unsigned int)(uintptr_t)l,
        16, 0, 0);
}

// ---- pack: wpack[hg][step(16)][Nt(16)][lane(64)][j(8)] bf16 ----
// col cp = hg*256 + Nt*16 + n16 ; Nt = wc*4 + gate ; h = hg*64 + wc*16 + n16
// value = W[gate][h][k], k = step*32 + (lane>>4)*8 + j
__global__ __launch_bounds__(256) void pack_kernel(
    const float* __restrict__ Wif, const float* __restrict__ Wii,
    const float* __restrict__ Wio, const float* __restrict__ Wig,
    const float* __restrict__ Whf, const float* __restrict__ Whi,
    const float* __restrict__ Who, const float* __restrict__ Whg,
    const float* __restrict__ bif, const float* __restrict__ bii,
    const float* __restrict__ bio, const float* __restrict__ big,
    const float* __restrict__ bhf, const float* __restrict__ bhi,
    const float* __restrict__ bho, const float* __restrict__ bhg,
    unsigned short* __restrict__ wpack, float* __restrict__ bpack)
{
    const int t = blockIdx.x * 256 + threadIdx.x;   // 0..65535
    const int n16  = t & 15;
    const int kg   = (t >> 4) & 3;
    const int Nt   = (t >> 6) & 15;
    const int step = (t >> 10) & 15;
    const int hg   = t >> 14;
    const int gate = Nt & 3;
    const int wc   = Nt >> 2;
    const int h    = hg * 64 + wc * 16 + n16;
    const int k0   = step * 32 + kg * 8;

    const float* Wi = (gate == 0) ? Wif : (gate == 1) ? Wii : (gate == 2) ? Wio : Wig;
    const float* Wh = (gate == 0) ? Whf : (gate == 1) ? Whi : (gate == 2) ? Who : Whg;
    const float* src = (k0 < 256) ? (Wi + h * 256 + k0) : (Wh + h * 256 + (k0 - 256));

    unsigned pk[4];
#pragma unroll
    for (int p = 0; p < 4; ++p)
        pk[p] = (unsigned)f2bf(src[p * 2]) | ((unsigned)f2bf(src[p * 2 + 1]) << 16);
    uint4 o4 = {pk[0], pk[1], pk[2], pk[3]};
    *(uint4*)&wpack[(size_t)t * 8] = o4;

    if (t < 1024) {
        const int cp = t;
        const int n2 = cp & 15, Nt2 = (cp >> 4) & 15, hg2 = cp >> 8;
        const int g2 = Nt2 & 3, wc2 = Nt2 >> 2;
        const int h2 = hg2 * 64 + wc2 * 16 + n2;
        const float* bi = (g2 == 0) ? bif : (g2 == 1) ? bii : (g2 == 2) ? bio : big;
        const float* bh = (g2 == 0) ? bhf : (g2 == 1) ? bhi : (g2 == 2) ? bho : bhg;
        bpack[cp] = bi[h2] + bh[h2];
    }
}

// ---- convert: xpack[panel(512)][step(16)][rt(8)][lane(64)][j(8)] bf16 ----
// row = panel*128 + rt*16 + (lane&15), k = step*32 + (lane>>4)*8 + j
__global__ __launch_bounds__(256) void convert_kernel(
    const float* __restrict__ input, const float* __restrict__ hidden,
    unsigned short* __restrict__ xpack)
{
    const int t = blockIdx.x * 256 + threadIdx.x;   // 0..4194303
    const int l     = t & 63;
    const int rt    = (t >> 6) & 7;
    const int step  = (t >> 9) & 15;
    const int panel = t >> 13;
    const int row = panel * 128 + rt * 16 + (l & 15);
    const int k0  = step * 32 + (l >> 4) * 8;
    const float* src = (k0 < 256) ? input + (size_t)row * 256 + k0
                                  : hidden + (size_t)row * 256 + (k0 - 256);
    float4 x0 = *(const float4*)src;
    float4 x1 = *(const float4*)(src + 4);
    uint4 o; o.x = pack2bf(x0.x, x0.y); o.y = pack2bf(x0.z, x0.w);
    o.z = pack2bf(x1.x, x1.y); o.w = pack2bf(x1.z, x1.w);
    *(uint4*)&xpack[(size_t)t * 8] = o;
}

// ---- K1: GEMM + gates. grid 2048 = 512 panels x 4 hg, block 512 (8 waves) ----
// Triple-buffered, stage-2-ahead, ONE barrier per step:
//   step k: vmcnt(3) -> barrier -> ds_read buf[k%3] -> STAGE(k+2) ->
//           setprio(1) 16 MFMA setprio(0)
// Safety: STAGE(k+2) overwrites buf[(k-1)%3]; its readers (step k-1 ds_reads)
// completed before reaching barrier(k) (lgkmcnt before MFMA(k-1)), and the
// staging wave passed barrier(k) first. vmcnt(3) drains own S(k), leaves
// S(k+1)'s 3 in flight.
__global__ __launch_bounds__(512, 4) void lstm_gemm_kernel(
    const unsigned short* __restrict__ xpack,
    const float* __restrict__ cell,
    const unsigned short* __restrict__ wpack, const float* __restrict__ bpack,
    float* __restrict__ out)
{
    // per buffer: A frags 4096 hw (8KB) + B frags 8192 hw (16KB) = 24 KB
    __shared__ unsigned short buf[3][12288];   // 72 KB -> 2 blocks/CU

    // XCD-bijective swizzle (2048 % 8 == 0): each XCD gets 64 panels x 4 hg
    const int swz = (blockIdx.x & 7) * 256 + (blockIdx.x >> 3);
    const int hg    = swz & 3;
    const int panel = swz >> 2;
    const int row0  = panel * 128;

    const int tid = threadIdx.x;
    const int w = tid >> 6, l = tid & 63;
    const int wr = w >> 2, wc = w & 3;

    const unsigned short* asrc = xpack + (size_t)panel * 65536 + w * 512 + l * 8;
    const unsigned short* wsrc = wpack + (size_t)hg * 131072 + w * 1024 + l * 8;

#define STAGE(s)                                                              \
    do {                                                                      \
        glds16(asrc + (size_t)(s) * 4096, &buf[(s) % 3][w * 512]);            \
        glds16(wsrc + (size_t)(s) * 8192, &buf[(s) % 3][4096 + w * 1024]);    \
        glds16(wsrc + (size_t)(s) * 8192 + 512,                               \
               &buf[(s) % 3][4096 + w * 1024 + 512]);                         \
    } while (0)

    // prologue: stage S0, S1 (6 glds in flight)
    STAGE(0);
    STAGE(1);

    f32x4 acc[4][4] = {};

#pragma unroll
    for (int k = 0; k < 16; ++k) {
        const int cur = k % 3;
        // drain own S(k) loads; S(k+1)'s stay in flight (none left at k=15)
        if (k < 14) asm volatile("s_waitcnt vmcnt(3)" ::: "memory");
        else        asm volatile("s_waitcnt vmcnt(0)" ::: "memory");
        __builtin_amdgcn_s_barrier();   // publishes S(k) staging completion

        short8 Af[4], Bf[4];
#pragma unroll
        for (int m = 0; m < 4; ++m)
            Af[m] = *(const short8*)&buf[cur][((wr * 4 + m) * 64 + l) << 3];
#pragma unroll
        for (int n = 0; n < 4; ++n)
            Bf[n] = *(const short8*)&buf[cur][4096 + (((wc * 4 + n) * 64 + l) << 3)];

        if (k + 2 < 16) STAGE(k + 2);   // overwrite buf[(k-1)%3] -- safe (see above)

        __builtin_amdgcn_s_setprio(1);
#pragma unroll
        for (int m = 0; m < 4; ++m)
#pragma unroll
            for (int n = 0; n < 4; ++n)
                acc[m][n] = __builtin_amdgcn_mfma_f32_16x16x32_bf16(Af[m], Bf[n], acc[m][n], 0, 0, 0);
        __builtin_amdgcn_s_setprio(0);
    }
#undef STAGE

    // ---- epilogue: bias + activations + cell update ----
    const int n16l = l & 15;
    const int lrow = l >> 4;
    const int hcol = hg * 64 + wc * 16 + n16l;
    float bias[4];
#pragma unroll
    for (int n = 0; n < 4; ++n)
        bias[n] = bpack[hg * 256 + wc * 64 + n * 16 + n16l];

#pragma unroll
    for (int m = 0; m < 4; ++m) {
#pragma unroll
        for (int rr = 0; rr < 4; ++rr) {
            const size_t rg_ = (size_t)row0 + wr * 64 + m * 16 + lrow * 4 + rr;
            const float fv = sigm(acc[m][0][rr] + bias[0]);
            const float iv = sigm(acc[m][1][rr] + bias[1]);
            const float ov = sigm(acc[m][2][rr] + bias[2]);
            const float gv = tanh_(acc[m][3][rr] + bias[3]);
            const float cv = cell[rg_ * 256 + hcol];
            const float nc = fv * cv + iv * gv;
            const float nhv = ov * tanh_(nc);
            out[(size_t)2 * BH + rg_ * 256 + hcol] = nc;
            out[(size_t)BH + rg_ * 256 + hcol] = nhv;
        }
    }
}

// ---- K2: log_softmax finalize. out[0..BH) = nh - log(sum(exp(nh))) ----
__global__ __launch_bounds__(256) void softmax_kernel(
    const float* __restrict__ nh, float* __restrict__ outp)
{
    const int w = threadIdx.x >> 6, l = threadIdx.x & 63;
#pragma unroll 1
    for (int it = 0; it < 8; ++it) {
        const size_t row = (size_t)it * 8192 + blockIdx.x * 4 + w;
        float4 v = *(const float4*)(nh + row * 256 + l * 4);
        float s = __expf(v.x) + __expf(v.y) + __expf(v.z) + __expf(v.w);
#pragma unroll
        for (int m = 1; m < 64; m <<= 1) s += __shfl_xor(s, m);
        const float lz = __logf(s);
        float4 o = {v.x - lz, v.y - lz, v.z - lz, v.w - lz};
        *(float4*)(outp + row * 256 + l * 4) = o;
    }
}

extern "C" void kernel_launch(void* const* d_in, const int* in_sizes, int n_in,
                              void* d_out, int out_size, void* d_ws, size_t ws_size,
                              hipStream_t stream)
{
    const float* input  = (const float*)d_in[0];
    const float* hidden = (const float*)d_in[1];
    const float* cell   = (const float*)d_in[2];
    const float* Wif = (const float*)d_in[3];  const float* bif = (const float*)d_in[4];
    const float* Wii = (const float*)d_in[5];  const float* bii = (const float*)d_in[6];
    const float* Wio = (const float*)d_in[7];  const float* bio = (const float*)d_in[8];
    const float* Wig = (const float*)d_in[9];  const float* big = (const float*)d_in[10];
    const float* Whf = (const float*)d_in[11]; const float* bhf = (const float*)d_in[12];
    const float* Whi = (const float*)d_in[13]; const float* bhi = (const float*)d_in[14];
    const float* Who = (const float*)d_in[15]; const float* bho = (const float*)d_in[16];
    const float* Whg = (const float*)d_in[17]; const float* bhg = (const float*)d_in[18];

    unsigned short* wpack = (unsigned short*)d_ws;                 // 1 MB
    float* bpack = (float*)((char*)d_ws + (size_t)1024 * 512 * 2); // 4 KB

    float* out = (float*)d_out;
    // xpack lives in out[0:BH) (exactly 64 MiB) — free until K2 overwrites it.
    unsigned short* xpack = (unsigned short*)d_out;

    hipLaunchKernelGGL(pack_kernel, dim3(256), dim3(256), 0, stream,
        Wif, Wii, Wio, Wig, Whf, Whi, Who, Whg,
        bif, bii, bio, big, bhf, bhi, bho, bhg, wpack, bpack);

    hipLaunchKernelGGL(convert_kernel, dim3(16384), dim3(256), 0, stream,
        input, hidden, xpack);

    hipLaunchKernelGGL(lstm_gemm_kernel, dim3(2048), dim3(512), 0, stream,
        xpack, cell, wpack, bpack, out);

    hipLaunchKernelGGL(softmax_kernel, dim3(2048), dim3(256), 0, stream,
        out + (size_t)BH, out);
}